// Round 6
// baseline (124.185 us; speedup 1.0000x reference)
//
#include <hip/hip_runtime.h>

#define QN 900
#define CN 256
#define NCAM 6
#define HF 112
#define WF 200
#define ZL 10
#define YL 128
#define XL 128
#define NT 512
#define RG 8               // rows per block = 2 groups of 4
#define NB 225             // 1800 / RG

// Raw barrier: LDS-producer drain only; does NOT drain vmcnt, so global
// loads stay in flight across it (unlike __syncthreads).
#define BAR() do { asm volatile("s_waitcnt lgkmcnt(0)" ::: "memory"); \
                   __builtin_amdgcn_s_barrier();                      \
                   asm volatile("" ::: "memory"); } while (0)

__global__ __launch_bounds__(NT, 2) void mafs_fused(
    const float* __restrict__ query,
    const float* __restrict__ rp,
    const float* __restrict__ imgf,
    const float* __restrict__ lidf,
    const float* __restrict__ l2i,
    const float* __restrict__ cam_w, const float* __restrict__ cam_b,
    const float* __restrict__ lid_w, const float* __restrict__ lid_b,
    const float* __restrict__ att_w1, const float* __restrict__ att_b1,
    const float* __restrict__ att_w2, const float* __restrict__ att_b2,
    const float* __restrict__ fus_w1, const float* __restrict__ fus_b1,
    const float* __restrict__ ln_g, const float* __restrict__ ln_b,
    const float* __restrict__ fus_w2, const float* __restrict__ fus_b2,
    float* __restrict__ out)
{
  const int blk = blockIdx.x;            // 0..224
  const int q0  = blk * RG;              // rows q0..q0+7
  const int tid = threadIdx.x;
  const int c    = tid & 255;            // channel
  const int h    = tid >> 8;             // 0/1: owns rows {2h,2h+1} per group
  const int lane = tid & 63;
  const int w    = tid >> 6;             // wave 0..7

  __shared__ float s_q[RG*CN];                 // 8 KB
  __shared__ float s_a[CN*RG],  s_b[CN*RG];    // raw feats   [c][rr]
  __shared__ float s_a2[CN*RG], s_b2[CN*RG];   // gated feats [c][rr]
  __shared__ float s_t[CN*RG];                 // post-LN     [c][rr]
  __shared__ float s_w0[RG], s_w1[RG];
  __shared__ float s_red[2*RG*4];

  // batch id per group (block 112 straddles: rows 896..899 b=0, 900..903 b=1)
  int bg[2];
  bg[0] = (q0) / QN;
  bg[1] = (q0 + 4) / QN;

  // ---- 1) rp loads (oldest) ----
  float rxx[2][2], ryy[2][2], rzz[2][2];
  #pragma unroll
  for (int gi = 0; gi < 2; ++gi)
    #pragma unroll
    for (int i = 0; i < 2; ++i) {
      const int row = q0 + gi*4 + 2*h + i;
      rxx[gi][i] = rp[row*3+0];
      ryy[gi][i] = rp[row*3+1];
      rzz[gi][i] = rp[row*3+2];
    }

  // ---- 2) query loads ----
  float qv[4];
  #pragma unroll
  for (int i = 0; i < 4; ++i)
    qv[i] = query[(size_t)q0*CN + i*NT + tid];

  // ---- 3) lidar: issue all 32 loads branchless ----
  float lv[2][2][8], lw_[2][2][8];
  #pragma unroll
  for (int gi = 0; gi < 2; ++gi) {
    const float* lbase = lidf + ((size_t)(bg[gi]*CN) + c) * (ZL*YL*XL);
    #pragma unroll
    for (int i = 0; i < 2; ++i) {
      const float x = rxx[gi][i]*(float)XL - 0.5f;
      const float y = ryy[gi][i]*(float)YL - 0.5f;
      const float z = rzz[gi][i]*(float)ZL - 0.5f;
      const float x0f = floorf(x), y0f = floorf(y), z0f = floorf(z);
      const int x0=(int)x0f, y0=(int)y0f, z0=(int)z0f;
      const float fx=x-x0f, fy=y-y0f, fz=z-z0f;
      const float wx[2]={1.f-fx,fx}, wy[2]={1.f-fy,fy}, wz[2]={1.f-fz,fz};
      #pragma unroll
      for (int dz = 0; dz < 2; ++dz)
        #pragma unroll
        for (int dy = 0; dy < 2; ++dy)
          #pragma unroll
          for (int dx = 0; dx < 2; ++dx) {
            const int xi=x0+dx, yi=y0+dy, zi=z0+dz;
            const bool ib = (xi>=0)&&(xi<XL)&&(yi>=0)&&(yi<YL)&&(zi>=0)&&(zi<ZL);
            const int xc=min(max(xi,0),XL-1);
            const int yc=min(max(yi,0),YL-1);
            const int zc=min(max(zi,0),ZL-1);
            const int t=(dz*2+dy)*2+dx;
            lv[gi][i][t]  = lbase[(zc*YL+yc)*XL+xc];
            lw_[gi][i][t] = ib ? wx[dx]*wy[dy]*wz[dz] : 0.f;
          }
    }
  }

  // ---- 4) stage query rows (waits qv only: qv older than lidar batch) ----
  #pragma unroll
  for (int i = 0; i < 4; ++i)
    s_q[i*NT + tid] = qv[i];
  BAR();

  // ---- 5) camera (branchy, wave-uniform valid; consumes overlap lidar drain) ----
  float fc[2][2] = {{0.f,0.f},{0.f,0.f}}, cnt[2][2] = {{0.f,0.f},{0.f,0.f}};
  #pragma unroll
  for (int gi = 0; gi < 2; ++gi) {
    #pragma unroll
    for (int n = 0; n < NCAM; ++n) {
      const float* M = l2i + (size_t)(bg[gi]*NCAM + n)*16;
      const float m0=M[0],m1=M[1],m2=M[2],m3=M[3];
      const float m4=M[4],m5=M[5],m6=M[6],m7=M[7];
      const float m8=M[8],m9=M[9],m10=M[10],m11=M[11];
      #pragma unroll
      for (int i = 0; i < 2; ++i) {
        const float ax = rxx[gi][i]*102.4f - 51.2f;
        const float ay = ryy[gi][i]*102.4f - 51.2f;
        const float az = rzz[gi][i]*8.0f   - 5.0f;
        const float c0 = m0*ax + m1*ay + m2 *az + m3;
        const float c1 = m4*ax + m5*ay + m6 *az + m7;
        const float c2 = m8*ax + m9*ay + m10*az + m11;
        const float dc = fmaxf(c2, 1e-5f);
        const float u = 2.0f * (c0 / dc) / 1599.0f - 1.0f;
        const float v = 2.0f * (c1 / dc) /  899.0f - 1.0f;
        const bool valid = (u >= -1.f) && (u <= 1.f) && (v >= -1.f) && (v <= 1.f)
                           && (c2 > 1e-5f);
        if (valid) {                    // uniform within wave
          cnt[gi][i] += 1.f;
          const float x = ((u + 1.f)*(float)WF - 1.f)*0.5f;
          const float y = ((v + 1.f)*(float)HF - 1.f)*0.5f;
          const float x0f = floorf(x), y0f = floorf(y);
          const int x0=(int)x0f, y0=(int)y0f;
          const float fx=x-x0f, fy=y-y0f;
          const bool xb0=(x0>=0)&&(x0<WF), xb1=(x0+1<WF)&&(x0+1>=0);
          const bool yb0=(y0>=0)&&(y0<HF), yb1=(y0+1<HF)&&(y0+1>=0);
          const float w00 = (xb0&&yb0) ? (1.f-fx)*(1.f-fy) : 0.f;
          const float w10 = (xb1&&yb0) ? fx*(1.f-fy)       : 0.f;
          const float w01 = (xb0&&yb1) ? (1.f-fx)*fy       : 0.f;
          const float w11 = (xb1&&yb1) ? fx*fy             : 0.f;
          const int xc0=min(max(x0,0),WF-1),  xc1=min(max(x0+1,0),WF-1);
          const int yc0=min(max(y0,0),HF-1),  yc1=min(max(y0+1,0),HF-1);
          const float* fb = imgf + ((size_t)((bg[gi]*NCAM + n)*CN) + c)*(HF*WF);
          const float t00 = fb[yc0*WF + xc0];
          const float t10 = fb[yc0*WF + xc1];
          const float t01 = fb[yc1*WF + xc0];
          const float t11 = fb[yc1*WF + xc1];
          fc[gi][i] += w00*t00 + w10*t10 + w01*t01 + w11*t11;
        }
      }
    }
  }
  #pragma unroll
  for (int gi = 0; gi < 2; ++gi)
    #pragma unroll
    for (int i = 0; i < 2; ++i)
      fc[gi][i] /= fmaxf(cnt[gi][i], 1.f);

  // ---- 6) attention gate: wave w owns row w (full k=0..255) ----
  {
    const float* qrow = s_q + w*CN;
    float hh = att_b1[lane];
    #pragma unroll 4
    for (int k = 0; k < CN; ++k) hh += qrow[k] * att_w1[k*64 + lane];
    hh = fmaxf(hh, 0.f);
    float l0 = hh * att_w2[2*lane], l1 = hh * att_w2[2*lane+1];
    #pragma unroll
    for (int o = 32; o > 0; o >>= 1) { l0 += __shfl_down(l0,o); l1 += __shfl_down(l1,o); }
    if (lane == 0) {
      l0 += att_b2[0]; l1 += att_b2[1];
      const float m  = fmaxf(l0, l1);
      const float e0 = expf(l0 - m), e1 = expf(l1 - m);
      const float inv = 1.f / (e0 + e1);
      s_w0[w] = e0 * inv; s_w1[w] = e1 * inv;
    }
  }
  // consumed after the stage BAR below

  // ---- 7) consume lidar ----
  float fl[2][2];
  #pragma unroll
  for (int gi = 0; gi < 2; ++gi)
    #pragma unroll
    for (int i = 0; i < 2; ++i) {
      float s = 0.f;
      #pragma unroll
      for (int t = 0; t < 8; ++t) s += lw_[gi][i][t] * lv[gi][i][t];
      fl[gi][i] = s;
    }

  // ---- 8) stage feats [c][rr] ----
  #pragma unroll
  for (int gi = 0; gi < 2; ++gi)
    #pragma unroll
    for (int i = 0; i < 2; ++i) {
      const int rr = gi*4 + 2*h + i;
      s_a[c*RG + rr] = fc[gi][i];
      s_b[c*RG + rr] = fl[gi][i];
    }
  BAR();

  // ---- 9) cam/lidar projections: 1 weight feeds 8 rows ----
  float pc[2][2] = {{0,0},{0,0}}, pl[2][2] = {{0,0},{0,0}};
  #pragma unroll 4
  for (int k = 0; k < CN; ++k) {
    const float wc = cam_w[k*CN + c];
    const float wl = lid_w[k*CN + c];
    #pragma unroll
    for (int gi = 0; gi < 2; ++gi) {
      const float2 xa = *(const float2*)&s_a[k*RG + gi*4 + 2*h];
      const float2 xb = *(const float2*)&s_b[k*RG + gi*4 + 2*h];
      pc[gi][0] += xa.x*wc; pc[gi][1] += xa.y*wc;
      pl[gi][0] += xb.x*wl; pl[gi][1] += xb.y*wl;
    }
  }
  {
    const float pcb = cam_b[c], plb = lid_b[c];
    #pragma unroll
    for (int gi = 0; gi < 2; ++gi)
      #pragma unroll
      for (int i = 0; i < 2; ++i) {
        const int rr = gi*4 + 2*h + i;
        s_a2[c*RG + rr] = s_w0[rr] * (pc[gi][i] + pcb);
        s_b2[c*RG + rr] = s_w1[rr] * (pl[gi][i] + plb);
      }
  }
  BAR();

  // ---- 10) fusion layer 1 (512 -> 256) ----
  float t1[2][2] = {{0,0},{0,0}};
  #pragma unroll 2
  for (int k = 0; k < CN; ++k) {
    const float wA = fus_w1[k*CN + c];
    const float wB = fus_w1[(size_t)(CN + k)*CN + c];
    #pragma unroll
    for (int gi = 0; gi < 2; ++gi) {
      const float2 xa = *(const float2*)&s_a2[k*RG + gi*4 + 2*h];
      const float2 xb = *(const float2*)&s_b2[k*RG + gi*4 + 2*h];
      t1[gi][0] += xa.x*wA + xb.x*wB;
      t1[gi][1] += xa.y*wA + xb.y*wB;
    }
  }
  {
    const float bb = fus_b1[c];
    #pragma unroll
    for (int gi = 0; gi < 2; ++gi) { t1[gi][0] += bb; t1[gi][1] += bb; }
  }

  // ---- 11) layer norm + relu (row rr reduced over its 4 waves) ----
  #pragma unroll
  for (int gi = 0; gi < 2; ++gi)
    #pragma unroll
    for (int i = 0; i < 2; ++i) {
      float s1 = t1[gi][i];
      #pragma unroll
      for (int o = 32; o > 0; o >>= 1) s1 += __shfl_down(s1, o);
      if (lane == 0) s_red[(gi*4 + 2*h + i)*4 + (w & 3)] = s1;
    }
  BAR();
  float mu[2][2];
  #pragma unroll
  for (int gi = 0; gi < 2; ++gi)
    #pragma unroll
    for (int i = 0; i < 2; ++i) {
      const int rr = gi*4 + 2*h + i;
      mu[gi][i] = (s_red[rr*4+0]+s_red[rr*4+1]+s_red[rr*4+2]+s_red[rr*4+3]) * (1.f/256.f);
    }
  #pragma unroll
  for (int gi = 0; gi < 2; ++gi)
    #pragma unroll
    for (int i = 0; i < 2; ++i) {
      const float d = t1[gi][i] - mu[gi][i];
      float s2 = d*d;
      #pragma unroll
      for (int o = 32; o > 0; o >>= 1) s2 += __shfl_down(s2, o);
      if (lane == 0) s_red[32 + (gi*4 + 2*h + i)*4 + (w & 3)] = s2;
    }
  BAR();
  {
    const float g = ln_g[c], be = ln_b[c];
    #pragma unroll
    for (int gi = 0; gi < 2; ++gi)
      #pragma unroll
      for (int i = 0; i < 2; ++i) {
        const int rr = gi*4 + 2*h + i;
        const float var = (s_red[32+rr*4+0]+s_red[32+rr*4+1]+s_red[32+rr*4+2]+s_red[32+rr*4+3]) * (1.f/256.f);
        const float ri = rsqrtf(var + 1e-5f);
        s_t[c*RG + rr] = fmaxf((t1[gi][i] - mu[gi][i]) * ri * g + be, 0.f);
      }
  }
  BAR();

  // ---- 12) output projection (256 -> 256) ----
  float o[2][2] = {{0,0},{0,0}};
  #pragma unroll 4
  for (int k = 0; k < CN; ++k) {
    const float wgt = fus_w2[k*CN + c];
    #pragma unroll
    for (int gi = 0; gi < 2; ++gi) {
      const float2 xt = *(const float2*)&s_t[k*RG + gi*4 + 2*h];
      o[gi][0] += xt.x*wgt; o[gi][1] += xt.y*wgt;
    }
  }
  {
    const float ob = fus_b2[c];
    #pragma unroll
    for (int gi = 0; gi < 2; ++gi)
      #pragma unroll
      for (int i = 0; i < 2; ++i)
        out[(size_t)(q0 + gi*4 + 2*h + i)*CN + c] = o[gi][i] + ob;
  }
}

extern "C" void kernel_launch(void* const* d_in, const int* in_sizes, int n_in,
                              void* d_out, int out_size, void* d_ws, size_t ws_size,
                              hipStream_t stream) {
  const float* query   = (const float*)d_in[0];
  const float* rpts    = (const float*)d_in[1];
  const float* imgf    = (const float*)d_in[2];
  const float* lidf    = (const float*)d_in[3];
  const float* l2i     = (const float*)d_in[4];
  const float* cam_w   = (const float*)d_in[5];
  const float* cam_b   = (const float*)d_in[6];
  const float* lid_w   = (const float*)d_in[7];
  const float* lid_b   = (const float*)d_in[8];
  const float* att_w1  = (const float*)d_in[9];
  const float* att_b1  = (const float*)d_in[10];
  const float* att_w2  = (const float*)d_in[11];
  const float* att_b2  = (const float*)d_in[12];
  const float* fus_w1  = (const float*)d_in[13];
  const float* fus_b1  = (const float*)d_in[14];
  const float* ln_g    = (const float*)d_in[15];
  const float* ln_b    = (const float*)d_in[16];
  const float* fus_w2  = (const float*)d_in[17];
  const float* fus_b2  = (const float*)d_in[18];
  float* out = (float*)d_out;

  dim3 grid(NB);     // 225
  dim3 block(NT);    // 512
  mafs_fused<<<grid, block, 0, stream>>>(
      query, rpts, imgf, lidf, l2i,
      cam_w, cam_b, lid_w, lid_b,
      att_w1, att_b1, att_w2, att_b2,
      fus_w1, fus_b1, ln_g, ln_b, fus_w2, fus_b2, out);
}

// Round 7
// 97.409 us; speedup vs baseline: 1.2749x; 1.2749x over previous
//
#include <hip/hip_runtime.h>

#define QN 900
#define CN 256
#define NCAM 6
#define HF 112
#define WF 200
#define ZL 10
#define YL 128
#define XL 128
#define R 4
#define NT 512

// Raw barrier: drains LDS ops only (lgkmcnt), NOT vmcnt -> global loads
// stay in flight across it (unlike __syncthreads' full vmcnt(0) drain).
#define BAR() do { asm volatile("s_waitcnt lgkmcnt(0)" ::: "memory"); \
                   __builtin_amdgcn_s_barrier();                      \
                   asm volatile("" ::: "memory"); } while (0)

__global__ __launch_bounds__(NT, 2) void mafs_fused(
    const float* __restrict__ query,
    const float* __restrict__ rp,
    const float* __restrict__ imgf,
    const float* __restrict__ lidf,
    const float* __restrict__ l2i,
    const float* __restrict__ cam_w, const float* __restrict__ cam_b,
    const float* __restrict__ lid_w, const float* __restrict__ lid_b,
    const float* __restrict__ att_w1, const float* __restrict__ att_b1,
    const float* __restrict__ att_w2, const float* __restrict__ att_b2,
    const float* __restrict__ fus_w1, const float* __restrict__ fus_b1,
    const float* __restrict__ ln_g, const float* __restrict__ ln_b,
    const float* __restrict__ fus_w2, const float* __restrict__ fus_b2,
    float* __restrict__ out)
{
  const int blk = blockIdx.x;            // 0..449
  const int q0  = blk * R;               // 4 rows, same batch (900 % 4 == 0)
  const int b   = q0 / QN;
  const int tid = threadIdx.x;
  const int c    = tid & 255;            // channel
  const int h    = tid >> 8;             // owns rows {2h, 2h+1}
  const int lane = tid & 63;
  const int w    = tid >> 6;             // wave 0..7

  __shared__ float s_q[R*CN];
  __shared__ float s_a[CN*R],  s_b[CN*R];    // raw feats   [c][r]
  __shared__ float s_a2[CN*R], s_b2[CN*R];   // gated feats [c][r]
  __shared__ float s_t[CN*R];                // post-LN     [c][r]
  __shared__ float s_hp[8*64];
  __shared__ float s_w0[R], s_w1[R];
  __shared__ float s_red[2*R*4];

  // ---- 1) rp loads (oldest vmem) ----
  float rxx[2], ryy[2], rzz[2];
  #pragma unroll
  for (int i = 0; i < 2; ++i) {
    const int row = q0 + 2*h + i;
    rxx[i] = rp[row*3+0];
    ryy[i] = rp[row*3+1];
    rzz[i] = rp[row*3+2];
  }

  // ---- 2) query loads (older than lidar; staging waits only these) ----
  float qv[2];
  #pragma unroll
  for (int i = 0; i < 2; ++i)
    qv[i] = query[(size_t)q0*CN + i*NT + tid];

  // ---- 3) lidar: issue all 16 loads branchless, consume much later ----
  float lv[2][8], lw_[2][8];
  {
    const float* lbase = lidf + ((size_t)(b*CN) + c) * (ZL*YL*XL);
    #pragma unroll
    for (int i = 0; i < 2; ++i) {
      const float x = rxx[i]*(float)XL - 0.5f;
      const float y = ryy[i]*(float)YL - 0.5f;
      const float z = rzz[i]*(float)ZL - 0.5f;
      const float x0f = floorf(x), y0f = floorf(y), z0f = floorf(z);
      const int x0=(int)x0f, y0=(int)y0f, z0=(int)z0f;
      const float fx=x-x0f, fy=y-y0f, fz=z-z0f;
      const float wx[2]={1.f-fx,fx}, wy[2]={1.f-fy,fy}, wz[2]={1.f-fz,fz};
      #pragma unroll
      for (int dz = 0; dz < 2; ++dz)
        #pragma unroll
        for (int dy = 0; dy < 2; ++dy)
          #pragma unroll
          for (int dx = 0; dx < 2; ++dx) {
            const int xi=x0+dx, yi=y0+dy, zi=z0+dz;
            const bool ib = (xi>=0)&&(xi<XL)&&(yi>=0)&&(yi<YL)&&(zi>=0)&&(zi<ZL);
            const int xc=min(max(xi,0),XL-1);
            const int yc=min(max(yi,0),YL-1);
            const int zc=min(max(zi,0),ZL-1);
            const int t=(dz*2+dy)*2+dx;
            lv[i][t]  = lbase[(zc*YL+yc)*XL+xc];
            lw_[i][t] = ib ? wx[dx]*wy[dy]*wz[dz] : 0.f;
          }
    }
  }

  // ---- 4) stage query rows (vmcnt waits qv only: qv older than lidar) ----
  #pragma unroll
  for (int i = 0; i < 2; ++i)
    s_q[i*NT + tid] = qv[i];
  BAR();

  // ---- 5) gate partials: wave w -> row w&3, k-half w>>2.
  //      att_w1 consumes progressively drain the older lidar loads ->
  //      gate FMAs overlap the lidar HBM latency. ----
  {
    const int rw = w & 3, kh = w >> 2;
    const float* qrow = s_q + rw*CN + kh*128;
    const float* w1p  = att_w1 + (size_t)(kh*128)*64;
    float hh = 0.f;
    #pragma unroll 4
    for (int k = 0; k < 128; ++k) hh += qrow[k] * w1p[k*64 + lane];
    s_hp[w*64 + lane] = hh;
  }
  BAR();

  // ---- 6) gate combine ----
  if (w < R) {
    float hh = s_hp[w*64 + lane] + s_hp[(w+4)*64 + lane] + att_b1[lane];
    hh = fmaxf(hh, 0.f);
    float l0 = hh * att_w2[2*lane], l1 = hh * att_w2[2*lane+1];
    #pragma unroll
    for (int o = 32; o > 0; o >>= 1) { l0 += __shfl_down(l0,o); l1 += __shfl_down(l1,o); }
    if (lane == 0) {
      l0 += att_b2[0]; l1 += att_b2[1];
      const float m  = fmaxf(l0, l1);
      const float e0 = expf(l0 - m), e1 = expf(l1 - m);
      const float inv = 1.f / (e0 + e1);
      s_w0[w] = e0 * inv; s_w1[w] = e1 * inv;
    }
  }
  // visibility to all waves via the stage-feats BAR below

  // ---- 7) camera (branchy, wave-uniform valid) ----
  float fc[2] = {0.f,0.f}, cnt[2] = {0.f,0.f};
  #pragma unroll
  for (int n = 0; n < NCAM; ++n) {
    const float* M = l2i + (size_t)(b*NCAM + n)*16;
    const float m0=M[0],m1=M[1],m2=M[2],m3=M[3];
    const float m4=M[4],m5=M[5],m6=M[6],m7=M[7];
    const float m8=M[8],m9=M[9],m10=M[10],m11=M[11];
    #pragma unroll
    for (int i = 0; i < 2; ++i) {
      const float ax = rxx[i]*102.4f - 51.2f;
      const float ay = ryy[i]*102.4f - 51.2f;
      const float az = rzz[i]*8.0f   - 5.0f;
      const float c0 = m0*ax + m1*ay + m2 *az + m3;
      const float c1 = m4*ax + m5*ay + m6 *az + m7;
      const float c2 = m8*ax + m9*ay + m10*az + m11;
      const float dc = fmaxf(c2, 1e-5f);
      const float u = 2.0f * (c0 / dc) / 1599.0f - 1.0f;
      const float v = 2.0f * (c1 / dc) /  899.0f - 1.0f;
      const bool valid = (u >= -1.f) && (u <= 1.f) && (v >= -1.f) && (v <= 1.f)
                         && (c2 > 1e-5f);
      if (valid) {                      // uniform within wave (h fixed per wave)
        cnt[i] += 1.f;
        const float x = ((u + 1.f)*(float)WF - 1.f)*0.5f;
        const float y = ((v + 1.f)*(float)HF - 1.f)*0.5f;
        const float x0f = floorf(x), y0f = floorf(y);
        const int x0=(int)x0f, y0=(int)y0f;
        const float fx=x-x0f, fy=y-y0f;
        const bool xb0=(x0>=0)&&(x0<WF), xb1=(x0+1<WF)&&(x0+1>=0);
        const bool yb0=(y0>=0)&&(y0<HF), yb1=(y0+1<HF)&&(y0+1>=0);
        const float w00 = (xb0&&yb0) ? (1.f-fx)*(1.f-fy) : 0.f;
        const float w10 = (xb1&&yb0) ? fx*(1.f-fy)       : 0.f;
        const float w01 = (xb0&&yb1) ? (1.f-fx)*fy       : 0.f;
        const float w11 = (xb1&&yb1) ? fx*fy             : 0.f;
        const int xc0=min(max(x0,0),WF-1),  xc1=min(max(x0+1,0),WF-1);
        const int yc0=min(max(y0,0),HF-1),  yc1=min(max(y0+1,0),HF-1);
        const float* fb = imgf + ((size_t)((b*NCAM + n)*CN) + c)*(HF*WF);
        const float t00 = fb[yc0*WF + xc0];
        const float t10 = fb[yc0*WF + xc1];
        const float t01 = fb[yc1*WF + xc0];
        const float t11 = fb[yc1*WF + xc1];
        fc[i] += w00*t00 + w10*t10 + w01*t01 + w11*t11;
      }
    }
  }
  #pragma unroll
  for (int i = 0; i < 2; ++i) fc[i] /= fmaxf(cnt[i], 1.f);

  // ---- 8) consume lidar (retired during gate+camera) ----
  float fl[2];
  #pragma unroll
  for (int i = 0; i < 2; ++i) {
    float s = 0.f;
    #pragma unroll
    for (int t = 0; t < 8; ++t) s += lw_[i][t] * lv[i][t];
    fl[i] = s;
  }

  // ---- 9) stage feats [c][r] ----
  #pragma unroll
  for (int i = 0; i < 2; ++i) {
    s_a[c*R + 2*h + i] = fc[i];
    s_b[c*R + 2*h + i] = fl[i];
  }
  BAR();

  // ---- 10) cam/lidar projections: 1 weight feeds 4 rows ----
  float pc[2] = {0,0}, pl[2] = {0,0};
  #pragma unroll 8
  for (int k = 0; k < CN; ++k) {
    const float wc = cam_w[k*CN + c];
    const float wl = lid_w[k*CN + c];
    const float2 xa = *(const float2*)&s_a[k*R + 2*h];
    const float2 xb = *(const float2*)&s_b[k*R + 2*h];
    pc[0] += xa.x*wc; pc[1] += xa.y*wc;
    pl[0] += xb.x*wl; pl[1] += xb.y*wl;
  }
  {
    const float pcb = cam_b[c], plb = lid_b[c];
    #pragma unroll
    for (int i = 0; i < 2; ++i) {
      const int r = 2*h + i;
      s_a2[c*R + r] = s_w0[r] * (pc[i] + pcb);
      s_b2[c*R + r] = s_w1[r] * (pl[i] + plb);
    }
  }
  BAR();

  // ---- 11) fusion layer 1 (512 -> 256) ----
  float t1[2] = {0,0};
  #pragma unroll 4
  for (int k = 0; k < CN; ++k) {
    const float wA = fus_w1[k*CN + c];
    const float wB = fus_w1[(size_t)(CN + k)*CN + c];
    const float2 xa = *(const float2*)&s_a2[k*R + 2*h];
    const float2 xb = *(const float2*)&s_b2[k*R + 2*h];
    t1[0] += xa.x*wA + xb.x*wB;
    t1[1] += xa.y*wA + xb.y*wB;
  }
  {
    const float bb = fus_b1[c];
    t1[0] += bb; t1[1] += bb;
  }

  // ---- 12) layer norm + relu ----
  #pragma unroll
  for (int i = 0; i < 2; ++i) {
    float s1 = t1[i];
    #pragma unroll
    for (int o = 32; o > 0; o >>= 1) s1 += __shfl_down(s1, o);
    if (lane == 0) s_red[(2*h+i)*4 + (w & 3)] = s1;
  }
  BAR();
  float mu[2];
  #pragma unroll
  for (int i = 0; i < 2; ++i) {
    const int r = 2*h + i;
    mu[i] = (s_red[r*4+0]+s_red[r*4+1]+s_red[r*4+2]+s_red[r*4+3]) * (1.f/256.f);
  }
  #pragma unroll
  for (int i = 0; i < 2; ++i) {
    const float d = t1[i] - mu[i];
    float s2 = d*d;
    #pragma unroll
    for (int o = 32; o > 0; o >>= 1) s2 += __shfl_down(s2, o);
    if (lane == 0) s_red[16 + (2*h+i)*4 + (w & 3)] = s2;
  }
  BAR();
  {
    const float g = ln_g[c], be = ln_b[c];
    #pragma unroll
    for (int i = 0; i < 2; ++i) {
      const int r = 2*h + i;
      const float var = (s_red[16+r*4+0]+s_red[16+r*4+1]+s_red[16+r*4+2]+s_red[16+r*4+3]) * (1.f/256.f);
      const float ri = rsqrtf(var + 1e-5f);
      s_t[c*R + r] = fmaxf((t1[i] - mu[i]) * ri * g + be, 0.f);
    }
  }
  BAR();

  // ---- 13) output projection (256 -> 256) ----
  float o[2] = {0,0};
  #pragma unroll 4
  for (int k = 0; k < CN; ++k) {
    const float wgt = fus_w2[k*CN + c];
    const float2 xt = *(const float2*)&s_t[k*R + 2*h];
    o[0] += xt.x*wgt; o[1] += xt.y*wgt;
  }
  {
    const float ob = fus_b2[c];
    #pragma unroll
    for (int i = 0; i < 2; ++i)
      out[(size_t)(q0 + 2*h + i)*CN + c] = o[i] + ob;
  }
}

extern "C" void kernel_launch(void* const* d_in, const int* in_sizes, int n_in,
                              void* d_out, int out_size, void* d_ws, size_t ws_size,
                              hipStream_t stream) {
  const float* query   = (const float*)d_in[0];
  const float* rpts    = (const float*)d_in[1];
  const float* imgf    = (const float*)d_in[2];
  const float* lidf    = (const float*)d_in[3];
  const float* l2i     = (const float*)d_in[4];
  const float* cam_w   = (const float*)d_in[5];
  const float* cam_b   = (const float*)d_in[6];
  const float* lid_w   = (const float*)d_in[7];
  const float* lid_b   = (const float*)d_in[8];
  const float* att_w1  = (const float*)d_in[9];
  const float* att_b1  = (const float*)d_in[10];
  const float* att_w2  = (const float*)d_in[11];
  const float* att_b2  = (const float*)d_in[12];
  const float* fus_w1  = (const float*)d_in[13];
  const float* fus_b1  = (const float*)d_in[14];
  const float* ln_g    = (const float*)d_in[15];
  const float* ln_b    = (const float*)d_in[16];
  const float* fus_w2  = (const float*)d_in[17];
  const float* fus_b2  = (const float*)d_in[18];
  float* out = (float*)d_out;

  dim3 grid((2*QN)/R);   // 450
  dim3 block(NT);        // 512
  mafs_fused<<<grid, block, 0, stream>>>(
      query, rpts, imgf, lidf, l2i,
      cam_w, cam_b, lid_w, lid_b,
      att_w1, att_b1, att_w2, att_b2,
      fus_w1, fus_b1, ln_g, ln_b, fus_w2, fus_b2, out);
}

// Round 8
// 96.509 us; speedup vs baseline: 1.2868x; 1.0093x over previous
//
#include <hip/hip_runtime.h>

#define QN 900
#define CN 256
#define NCAM 6
#define HF 112
#define WF 200
#define ZL 10
#define YL 128
#define XL 128
#define R 4
#define NT 512

__global__ __launch_bounds__(NT, 4) void mafs_fused(
    const float* __restrict__ query,
    const float* __restrict__ rp,
    const float* __restrict__ imgf,
    const float* __restrict__ lidf,
    const float* __restrict__ l2i,
    const float* __restrict__ cam_w, const float* __restrict__ cam_b,
    const float* __restrict__ lid_w, const float* __restrict__ lid_b,
    const float* __restrict__ att_w1, const float* __restrict__ att_b1,
    const float* __restrict__ att_w2, const float* __restrict__ att_b2,
    const float* __restrict__ fus_w1, const float* __restrict__ fus_b1,
    const float* __restrict__ ln_g, const float* __restrict__ ln_b,
    const float* __restrict__ fus_w2, const float* __restrict__ fus_b2,
    float* __restrict__ out)
{
  const int blk = blockIdx.x;            // 0..449
  const int q0  = blk * R;               // 4 rows, same batch (900 % 4 == 0)
  const int b   = q0 / QN;
  const int tid = threadIdx.x;
  const int c    = tid & 255;            // channel
  const int h    = tid >> 8;             // row-pair owner: rows {2h, 2h+1}
  const int lane = tid & 63;
  const int w    = tid >> 6;             // wave 0..7

  __shared__ float s_q[R*CN];
  __shared__ float s_a[CN*R], s_b[CN*R], s_t[CN*R];
  __shared__ float s_hp[8*64];
  __shared__ float s_w0[R], s_w1[R];
  __shared__ float s_red[2*R*4];

  // ---- stage 4 query rows (coalesced) ----
  #pragma unroll
  for (int i = 0; i < 2; ++i)
    s_q[i*NT + tid] = query[(size_t)q0*CN + i*NT + tid];
  __syncthreads();

  // ---- attention gate partials: wave w -> row w&3, k-half w>>2 ----
  {
    const int rw = w & 3, kh = w >> 2;
    const float* qrow = s_q + rw*CN + kh*128;
    const float* w1p  = att_w1 + (size_t)(kh*128)*64;
    float hh = 0.f;
    #pragma unroll 4
    for (int k = 0; k < 128; ++k) hh += qrow[k] * w1p[k*64 + lane];
    s_hp[w*64 + lane] = hh;
  }
  __syncthreads();
  if (w < R) {
    float hh = s_hp[w*64 + lane] + s_hp[(w+4)*64 + lane] + att_b1[lane];
    hh = fmaxf(hh, 0.f);
    float l0 = hh * att_w2[2*lane], l1 = hh * att_w2[2*lane+1];
    #pragma unroll
    for (int o = 32; o > 0; o >>= 1) { l0 += __shfl_down(l0,o); l1 += __shfl_down(l1,o); }
    if (lane == 0) {
      l0 += att_b2[0]; l1 += att_b2[1];
      const float m  = fmaxf(l0, l1);
      const float e0 = expf(l0 - m), e1 = expf(l1 - m);
      const float inv = 1.f / (e0 + e1);
      s_w0[w] = e0 * inv; s_w1[w] = e1 * inv;
    }
  }
  // no barrier here: s_w0/s_w1 consumed after the post-gather barrier

  // ---- reference points for this thread's two rows ----
  float rxx[2], ryy[2], rzz[2];
  #pragma unroll
  for (int i = 0; i < 2; ++i) {
    const int r = 2*h + i;
    rxx[i] = rp[(q0+r)*3+0];
    ryy[i] = rp[(q0+r)*3+1];
    rzz[i] = rp[(q0+r)*3+2];
  }

  // ---- LIDAR: issue all 16 loads branchless, consume after camera ----
  float lv[2][8], lw_[2][8];
  {
    const float* lbase = lidf + ((size_t)(b*CN) + c) * (ZL*YL*XL);
    #pragma unroll
    for (int i = 0; i < 2; ++i) {
      const float x = rxx[i]*(float)XL - 0.5f;
      const float y = ryy[i]*(float)YL - 0.5f;
      const float z = rzz[i]*(float)ZL - 0.5f;
      const float x0f = floorf(x), y0f = floorf(y), z0f = floorf(z);
      const int x0=(int)x0f, y0=(int)y0f, z0=(int)z0f;
      const float fx=x-x0f, fy=y-y0f, fz=z-z0f;
      const float wx[2]={1.f-fx,fx}, wy[2]={1.f-fy,fy}, wz[2]={1.f-fz,fz};
      #pragma unroll
      for (int dz = 0; dz < 2; ++dz)
        #pragma unroll
        for (int dy = 0; dy < 2; ++dy)
          #pragma unroll
          for (int dx = 0; dx < 2; ++dx) {
            const int xi=x0+dx, yi=y0+dy, zi=z0+dz;
            const bool ib = (xi>=0)&&(xi<XL)&&(yi>=0)&&(yi<YL)&&(zi>=0)&&(zi<ZL);
            const int xc=min(max(xi,0),XL-1);
            const int yc=min(max(yi,0),YL-1);
            const int zc=min(max(zi,0),ZL-1);
            const int t=(dz*2+dy)*2+dx;
            lv[i][t]  = lbase[(zc*YL+yc)*XL+xc];
            lw_[i][t] = ib ? wx[dx]*wy[dy]*wz[dz] : 0.f;
          }
    }
  }

  // ---- CAMERA: wave-uniform valid branch, clamp+masked-weight taps ----
  float fc[2] = {0.f,0.f}, cnt[2] = {0.f,0.f};
  #pragma unroll
  for (int n = 0; n < NCAM; ++n) {
    const float* M = l2i + (size_t)(b*NCAM + n)*16;
    const float m0=M[0],m1=M[1],m2=M[2],m3=M[3];
    const float m4=M[4],m5=M[5],m6=M[6],m7=M[7];
    const float m8=M[8],m9=M[9],m10=M[10],m11=M[11];
    #pragma unroll
    for (int i = 0; i < 2; ++i) {
      const float ax = rxx[i]*102.4f - 51.2f;
      const float ay = ryy[i]*102.4f - 51.2f;
      const float az = rzz[i]*8.0f   - 5.0f;
      const float c0 = m0*ax + m1*ay + m2 *az + m3;
      const float c1 = m4*ax + m5*ay + m6 *az + m7;
      const float c2 = m8*ax + m9*ay + m10*az + m11;
      const float dc = fmaxf(c2, 1e-5f);
      const float u = 2.0f * (c0 / dc) / 1599.0f - 1.0f;
      const float v = 2.0f * (c1 / dc) /  899.0f - 1.0f;
      const bool valid = (u >= -1.f) && (u <= 1.f) && (v >= -1.f) && (v <= 1.f)
                         && (c2 > 1e-5f);
      if (valid) {                      // uniform within wave (h fixed per wave)
        cnt[i] += 1.f;
        const float x = ((u + 1.f)*(float)WF - 1.f)*0.5f;
        const float y = ((v + 1.f)*(float)HF - 1.f)*0.5f;
        const float x0f = floorf(x), y0f = floorf(y);
        const int x0=(int)x0f, y0=(int)y0f;
        const float fx=x-x0f, fy=y-y0f;
        const bool xb0=(x0>=0)&&(x0<WF), xb1=(x0+1<WF)&&(x0+1>=0);
        const bool yb0=(y0>=0)&&(y0<HF), yb1=(y0+1<HF)&&(y0+1>=0);
        const float w00 = (xb0&&yb0) ? (1.f-fx)*(1.f-fy) : 0.f;
        const float w10 = (xb1&&yb0) ? fx*(1.f-fy)       : 0.f;
        const float w01 = (xb0&&yb1) ? (1.f-fx)*fy       : 0.f;
        const float w11 = (xb1&&yb1) ? fx*fy             : 0.f;
        const int xc0=min(max(x0,0),WF-1),  xc1=min(max(x0+1,0),WF-1);
        const int yc0=min(max(y0,0),HF-1),  yc1=min(max(y0+1,0),HF-1);
        const float* fb = imgf + ((size_t)((b*NCAM + n)*CN) + c)*(HF*WF);
        const float t00 = fb[yc0*WF + xc0];
        const float t10 = fb[yc0*WF + xc1];
        const float t01 = fb[yc1*WF + xc0];
        const float t11 = fb[yc1*WF + xc1];
        fc[i] += w00*t00 + w10*t10 + w01*t01 + w11*t11;
      }
    }
  }
  #pragma unroll
  for (int i = 0; i < 2; ++i) fc[i] /= fmaxf(cnt[i], 1.f);

  // ---- consume lidar (loads have been in flight through camera phase) ----
  float fl[2];
  #pragma unroll
  for (int i = 0; i < 2; ++i) {
    float s = 0.f;
    #pragma unroll
    for (int t = 0; t < 8; ++t) s += lw_[i][t] * lv[i][t];
    fl[i] = s;
  }

  #pragma unroll
  for (int i = 0; i < 2; ++i) {
    s_a[c*R + 2*h + i] = fc[i];
    s_b[c*R + 2*h + i] = fl[i];
  }
  __syncthreads();

  // ---- cam/lidar projections: weight col c feeds 4 rows (2 per thread) ----
  float pc[2] = {0,0}, pl[2] = {0,0};
  #pragma unroll 8
  for (int k = 0; k < CN; ++k) {
    const float wc = cam_w[k*CN + c];
    const float wl = lid_w[k*CN + c];
    const float2 xa = *(const float2*)&s_a[k*R + 2*h];
    const float2 xb = *(const float2*)&s_b[k*R + 2*h];
    pc[0] += xa.x*wc; pc[1] += xa.y*wc;
    pl[0] += xb.x*wl; pl[1] += xb.y*wl;
  }
  const float pcb = cam_b[c], plb = lid_b[c];
  __syncthreads();
  #pragma unroll
  for (int i = 0; i < 2; ++i) {
    const int r = 2*h + i;
    s_a[c*R + r] = s_w0[r] * (pc[i] + pcb);
    s_b[c*R + r] = s_w1[r] * (pl[i] + plb);
  }
  __syncthreads();

  // ---- fusion layer 1 (512 -> 256) ----
  float t1[2] = {0,0};
  #pragma unroll 4
  for (int k = 0; k < CN; ++k) {
    const float wA = fus_w1[k*CN + c];
    const float wB = fus_w1[(size_t)(CN + k)*CN + c];
    const float2 xa = *(const float2*)&s_a[k*R + 2*h];
    const float2 xb = *(const float2*)&s_b[k*R + 2*h];
    t1[0] += xa.x*wA + xb.x*wB;
    t1[1] += xa.y*wA + xb.y*wB;
  }
  {
    const float bb = fus_b1[c];
    t1[0] += bb; t1[1] += bb;
  }

  // ---- layer norm + relu (row r reduced across the 4 waves of its h-group) ----
  #pragma unroll
  for (int i = 0; i < 2; ++i) {
    float s1 = t1[i];
    #pragma unroll
    for (int o = 32; o > 0; o >>= 1) s1 += __shfl_down(s1, o);
    if (lane == 0) s_red[(2*h+i)*4 + (w & 3)] = s1;
  }
  __syncthreads();
  float mu[2];
  #pragma unroll
  for (int i = 0; i < 2; ++i) {
    const int r = 2*h + i;
    mu[i] = (s_red[r*4+0]+s_red[r*4+1]+s_red[r*4+2]+s_red[r*4+3]) * (1.f/256.f);
  }
  #pragma unroll
  for (int i = 0; i < 2; ++i) {
    const float d = t1[i] - mu[i];
    float s2 = d*d;
    #pragma unroll
    for (int o = 32; o > 0; o >>= 1) s2 += __shfl_down(s2, o);
    if (lane == 0) s_red[16 + (2*h+i)*4 + (w & 3)] = s2;
  }
  __syncthreads();
  {
    const float g = ln_g[c], be = ln_b[c];
    #pragma unroll
    for (int i = 0; i < 2; ++i) {
      const int r = 2*h + i;
      const float var = (s_red[16+r*4+0]+s_red[16+r*4+1]+s_red[16+r*4+2]+s_red[16+r*4+3]) * (1.f/256.f);
      const float ri = rsqrtf(var + 1e-5f);
      s_t[c*R + r] = fmaxf((t1[i] - mu[i]) * ri * g + be, 0.f);
    }
  }
  __syncthreads();

  // ---- output projection (256 -> 256) ----
  float o[2] = {0,0};
  #pragma unroll 4
  for (int k = 0; k < CN; ++k) {
    const float wgt = fus_w2[k*CN + c];
    const float2 xt = *(const float2*)&s_t[k*R + 2*h];
    o[0] += xt.x*wgt; o[1] += xt.y*wgt;
  }
  const float ob = fus_b2[c];
  #pragma unroll
  for (int i = 0; i < 2; ++i)
    out[(size_t)(q0 + 2*h + i)*CN + c] = o[i] + ob;
}

extern "C" void kernel_launch(void* const* d_in, const int* in_sizes, int n_in,
                              void* d_out, int out_size, void* d_ws, size_t ws_size,
                              hipStream_t stream) {
  const float* query   = (const float*)d_in[0];
  const float* rpts    = (const float*)d_in[1];
  const float* imgf    = (const float*)d_in[2];
  const float* lidf    = (const float*)d_in[3];
  const float* l2i     = (const float*)d_in[4];
  const float* cam_w   = (const float*)d_in[5];
  const float* cam_b   = (const float*)d_in[6];
  const float* lid_w   = (const float*)d_in[7];
  const float* lid_b   = (const float*)d_in[8];
  const float* att_w1  = (const float*)d_in[9];
  const float* att_b1  = (const float*)d_in[10];
  const float* att_w2  = (const float*)d_in[11];
  const float* att_b2  = (const float*)d_in[12];
  const float* fus_w1  = (const float*)d_in[13];
  const float* fus_b1  = (const float*)d_in[14];
  const float* ln_g    = (const float*)d_in[15];
  const float* ln_b    = (const float*)d_in[16];
  const float* fus_w2  = (const float*)d_in[17];
  const float* fus_b2  = (const float*)d_in[18];
  float* out = (float*)d_out;

  dim3 grid((2*QN)/R);   // 450
  dim3 block(NT);        // 512
  mafs_fused<<<grid, block, 0, stream>>>(
      query, rpts, imgf, lidf, l2i,
      cam_w, cam_b, lid_w, lid_b,
      att_w1, att_b1, att_w2, att_b2,
      fus_w1, fus_b1, ln_g, ln_b, fus_w2, fus_b2, out);
}